// Round 5
// baseline (1721.849 us; speedup 1.0000x reference)
//
#include <hip/hip_runtime.h>

#define VOCAB 50257
#define NB 512
#define NT 2048
#define NOUT 128
#define L2E 1.4426950408889634f

// sigmoid with pre-scaled arg (x' = log2e * x): sig = 1/(1+2^-x')
__device__ __forceinline__ float sig_s(float xs){
    return __builtin_amdgcn_rcpf(1.0f + __builtin_amdgcn_exp2f(-xs));
}
// tanh with pre-scaled arg (x' = 2*log2e * x): tanh = 1 - 2/(1+2^x')
__device__ __forceinline__ float tanh_s2(float xs2){
    return fmaf(-2.0f, __builtin_amdgcn_rcpf(1.0f + __builtin_amdgcn_exp2f(xs2)), 1.0f);
}
// tanh, natural arg (for tanh(c))
__device__ __forceinline__ float tanh_n(float x){
    return fmaf(-2.0f, __builtin_amdgcn_rcpf(1.0f + __builtin_amdgcn_exp2f(2.8853900817779268f*x)), 1.0f);
}

// K1: tab[v][j] = scale[j] * (b0[j] + sum_d emb[v][d]*Wih0[j][d]),  j = i0,i1,f0,f1,g0,g1,o0,o1
__global__ __launch_bounds__(256) void build_table(const float* __restrict__ emb,
                                                   const float* __restrict__ Wih0,
                                                   const float* __restrict__ b0,
                                                   float* __restrict__ tab){
    int v = blockIdx.x*256 + threadIdx.x;
    if (v >= VOCAB) return;
    const float4* ep = (const float4*)(emb + (size_t)v*8);
    float4 e0 = ep[0], e1 = ep[1];
    float e[8] = {e0.x,e0.y,e0.z,e0.w,e1.x,e1.y,e1.z,e1.w};
    float o[8];
#pragma unroll
    for (int j=0;j<8;j++){
        float s = b0[j];
#pragma unroll
        for (int d=0;d<8;d++) s = fmaf(e[d], Wih0[j*8+d], s);
        o[j] = s * ((j==4||j==5) ? 2.0f*L2E : L2E);
    }
    float4* tp = (float4*)(tab + (size_t)v*8);
    tp[0] = make_float4(o[0],o[1],o[2],o[3]);
    tp[1] = make_float4(o[4],o[5],o[6],o[7]);
}

// K2: 1 lane per batch row, ONE block of 512 threads = 8 waves on 1 CU
// (2 waves/SIMD so co-resident waves hide memory stalls; whole table lives in
//  this XCD's private L2 after warm-up). Token prefetch depth 5, gather depth 2.
__global__ __launch_bounds__(512) void lstm_scan(const int* __restrict__ x,
                                                 const float* __restrict__ tab,
                                                 const float* __restrict__ Whh0,
                                                 const float* __restrict__ Wih1,
                                                 const float* __restrict__ Whh1,
                                                 const float* __restrict__ b1,
                                                 float* __restrict__ y1out,   // [T][B][2]
                                                 float* __restrict__ tail){
    const int row = threadIdx.x;     // 512 rows, single block
    float w0[8][2], wi[8][2], wh[8][2], bb[8];
#pragma unroll
    for (int j=0;j<8;j++){
        float s = (j==4||j==5) ? 2.0f*L2E : L2E;
        w0[j][0]=Whh0[j*2+0]*s;  w0[j][1]=Whh0[j*2+1]*s;
        wi[j][0]=Wih1[j*2+0]*s;  wi[j][1]=Wih1[j*2+1]*s;
        wh[j][0]=Whh1[j*2+0]*s;  wh[j][1]=Whh1[j*2+1]*s;
        bb[j]=b1[j]*s;
    }
    const int* __restrict__ xr = x + (size_t)row*NT;
    const float4* __restrict__ tab4 = (const float4*)tab;
    float h00=0.f,h01=0.f,c00=0.f,c01=0.f;
    float h10=0.f,h11=0.f,c10=0.f,c11=0.f;
    // pipeline: at iter t, load token t+5; issue gather for token t+2; consume gather t.
    int ti2 = xr[2], ti3 = xr[3], ti4 = xr[4];
    const int t0v = xr[0], t1v = xr[1];
    float4 ga0 = tab4[(size_t)t0v*2], gb0 = tab4[(size_t)t0v*2+1];
    float4 ga1 = tab4[(size_t)t1v*2], gb1 = tab4[(size_t)t1v*2+1];
    float2* __restrict__ yp = (float2*)y1out + row;
    for (int t=0;t<NT;t++){
        int t5 = t+5; t5 = (t5 < NT) ? t5 : (NT-1);
        const int ti5 = xr[t5];
        const float4 ga2 = tab4[(size_t)ti2*2];
        const float4 gb2 = tab4[(size_t)ti2*2+1];
        // ---- layer 0: gate[j] = gx[j] + W0[j]·h0  (all pre-scaled) ----
        float p0 = fmaf(w0[0][0],h00, fmaf(w0[0][1],h01, ga0.x));
        float p1 = fmaf(w0[1][0],h00, fmaf(w0[1][1],h01, ga0.y));
        float p2 = fmaf(w0[2][0],h00, fmaf(w0[2][1],h01, ga0.z));
        float p3 = fmaf(w0[3][0],h00, fmaf(w0[3][1],h01, ga0.w));
        float p4 = fmaf(w0[4][0],h00, fmaf(w0[4][1],h01, gb0.x));
        float p5 = fmaf(w0[5][0],h00, fmaf(w0[5][1],h01, gb0.y));
        float p6 = fmaf(w0[6][0],h00, fmaf(w0[6][1],h01, gb0.z));
        float p7 = fmaf(w0[7][0],h00, fmaf(w0[7][1],h01, gb0.w));
        float si0=sig_s(p0), si1=sig_s(p1), sf0=sig_s(p2), sf1=sig_s(p3);
        float tg0=tanh_s2(p4), tg1=tanh_s2(p5), so0=sig_s(p6), so1=sig_s(p7);
        c00 = fmaf(sf0,c00, si0*tg0);
        c01 = fmaf(sf1,c01, si1*tg1);
        h00 = so0*tanh_n(c00);
        h01 = so1*tanh_n(c01);
        // ---- layer 1: gate[j] = bb[j] + Wi[j]·h0 + Wh[j]·h1 ----
        float q0 = fmaf(wh[0][0],h10, fmaf(wh[0][1],h11, fmaf(wi[0][0],h00, fmaf(wi[0][1],h01, bb[0]))));
        float q1 = fmaf(wh[1][0],h10, fmaf(wh[1][1],h11, fmaf(wi[1][0],h00, fmaf(wi[1][1],h01, bb[1]))));
        float q2 = fmaf(wh[2][0],h10, fmaf(wh[2][1],h11, fmaf(wi[2][0],h00, fmaf(wi[2][1],h01, bb[2]))));
        float q3 = fmaf(wh[3][0],h10, fmaf(wh[3][1],h11, fmaf(wi[3][0],h00, fmaf(wi[3][1],h01, bb[3]))));
        float q4 = fmaf(wh[4][0],h10, fmaf(wh[4][1],h11, fmaf(wi[4][0],h00, fmaf(wi[4][1],h01, bb[4]))));
        float q5 = fmaf(wh[5][0],h10, fmaf(wh[5][1],h11, fmaf(wi[5][0],h00, fmaf(wi[5][1],h01, bb[5]))));
        float q6 = fmaf(wh[6][0],h10, fmaf(wh[6][1],h11, fmaf(wi[6][0],h00, fmaf(wi[6][1],h01, bb[6]))));
        float q7 = fmaf(wh[7][0],h10, fmaf(wh[7][1],h11, fmaf(wi[7][0],h00, fmaf(wi[7][1],h01, bb[7]))));
        float ti0=sig_s(q0), ti1=sig_s(q1), tf0=sig_s(q2), tf1=sig_s(q3);
        float th0=tanh_s2(q4), th1=tanh_s2(q5), to0=sig_s(q6), to1=sig_s(q7);
        c10 = fmaf(tf0,c10, ti0*th0);
        c11 = fmaf(tf1,c11, ti1*th1);
        h10 = to0*tanh_n(c10);
        h11 = to1*tanh_n(c11);
        *yp = make_float2(h10,h11);
        yp += NB;
        ga0=ga1; gb0=gb1; ga1=ga2; gb1=gb2;
        ti2=ti3; ti3=ti4; ti4=ti5;
    }
    float2* __restrict__ t2 = (float2*)tail;    // h_n[2][B][2], c_n[2][B][2]
    t2[row]        = make_float2(h00,h01);
    t2[NB + row]   = make_float2(h10,h11);
    t2[2*NB + row] = make_float2(c00,c01);
    t2[3*NB + row] = make_float2(c10,c11);
}

// K3: out[bt][j] = y1[bt]·Wfc[j][:] + bfc[j]; one float4 store per thread.
__global__ __launch_bounds__(256) void fc_out(const float* __restrict__ y1,
                                              const float* __restrict__ Wfc,
                                              const float* __restrict__ bfc,
                                              float* __restrict__ out){
    const int tid = threadIdx.x;
    const int j4  = tid & 31;        // 32 threads cover 128 outputs (x4)
    const int btl = tid >> 5;        // 8 (b,t) pairs per block
    const int bt  = blockIdx.x*8 + btl;
    const int b   = bt >> 11;        // /T
    const int tt  = bt & (NT-1);
    const float2 y  = *(const float2*)(y1 + ((size_t)tt*NB + b)*2);
    const float4 wa = *(const float4*)(Wfc + j4*8);
    const float4 wb = *(const float4*)(Wfc + j4*8+4);
    const float4 bbv= *(const float4*)(bfc + j4*4);
    float4 o;
    o.x = fmaf(y.x,wa.x, fmaf(y.y,wa.y, bbv.x));
    o.y = fmaf(y.x,wa.z, fmaf(y.y,wa.w, bbv.y));
    o.z = fmaf(y.x,wb.x, fmaf(y.y,wb.y, bbv.z));
    o.w = fmaf(y.x,wb.z, fmaf(y.y,wb.w, bbv.w));
    *(float4*)(out + (size_t)bt*128 + j4*4) = o;
}

extern "C" void kernel_launch(void* const* d_in, const int* in_sizes, int n_in,
                              void* d_out, int out_size, void* d_ws, size_t ws_size,
                              hipStream_t stream){
    const int*   x    = (const int*)d_in[0];
    const float* emb  = (const float*)d_in[1];
    const float* Wih0 = (const float*)d_in[2];
    const float* Whh0 = (const float*)d_in[3];
    const float* b0   = (const float*)d_in[4];
    const float* Wih1 = (const float*)d_in[5];
    const float* Whh1 = (const float*)d_in[6];
    const float* b1   = (const float*)d_in[7];
    const float* Wfc  = (const float*)d_in[8];
    const float* bfc  = (const float*)d_in[9];
    float* out  = (float*)d_out;
    float* tab  = (float*)d_ws;                       // VOCAB*8 floats = 1.6 MB
    float* y1   = tab + (size_t)VOCAB*8;              // T*B*2 floats = 8 MB
    float* tail = out + (size_t)NB*NT*NOUT;           // h_n|c_n region of d_out

    build_table<<<(VOCAB+255)/256, 256, 0, stream>>>(emb, Wih0, b0, tab);
    lstm_scan<<<1, 512, 0, stream>>>(x, tab, Whh0, Wih1, Whh1, b1, y1, tail);
    fc_out<<<(NB*NT)/8, 256, 0, stream>>>(y1, Wfc, bfc, out);
}

// Round 6
// 548.139 us; speedup vs baseline: 3.1413x; 3.1413x over previous
//
#include <hip/hip_runtime.h>

#define VOCAB 50257
#define NB 512
#define NT 2048
#define NOUT 128
#define L2E 1.4426950408889634f

__device__ __forceinline__ float sig_s(float xs){   // arg pre-scaled by log2e
    return __builtin_amdgcn_rcpf(1.0f + __builtin_amdgcn_exp2f(-xs));
}
__device__ __forceinline__ float tanh_s2(float xs2){ // arg pre-scaled by 2*log2e
    return fmaf(-2.0f, __builtin_amdgcn_rcpf(1.0f + __builtin_amdgcn_exp2f(xs2)), 1.0f);
}
__device__ __forceinline__ float tanh_n(float x){    // natural arg (tanh(c))
    return fmaf(-2.0f, __builtin_amdgcn_rcpf(1.0f + __builtin_amdgcn_exp2f(2.8853900817779268f*x)), 1.0f);
}

// K1: tab[v][k][g] = s(j)*(b0[j] + emb[v]·Wih0[j]),  j=2g+k, g∈{i,f,g,o}
// s = log2e for i/f/o, 2*log2e for g. Lane k of a row pair reads tab[v][k][:] as one float4.
__global__ __launch_bounds__(256) void build_table(const float* __restrict__ emb,
                                                   const float* __restrict__ Wih0,
                                                   const float* __restrict__ b0,
                                                   float* __restrict__ tab){
    int v = blockIdx.x*256 + threadIdx.x;
    if (v >= VOCAB) return;
    const float4* ep = (const float4*)(emb + (size_t)v*8);
    float4 e0 = ep[0], e1 = ep[1];
    float e[8] = {e0.x,e0.y,e0.z,e0.w,e1.x,e1.y,e1.z,e1.w};
    float o[8];
#pragma unroll
    for (int j=0;j<8;j++){
        float s = b0[j];
#pragma unroll
        for (int d=0;d<8;d++) s = fmaf(e[d], Wih0[j*8+d], s);
        o[j] = s * ((j==4||j==5) ? 2.0f*L2E : L2E);
    }
    float4* tp = (float4*)(tab + (size_t)v*8);
    tp[0] = make_float4(o[0],o[2],o[4],o[6]);  // k=0: (i0,f0,g0,o0)
    tp[1] = make_float4(o[1],o[3],o[5],o[7]);  // k=1: (i1,f1,g1,o1)
}

// K1b: gx[t][b][k] = tab[x[b][t]][k]  — massively parallel gather, all CUs.
__global__ __launch_bounds__(256) void expand_gates(const int* __restrict__ x,
                                                    const float* __restrict__ tab,
                                                    float4* __restrict__ gx){
    int gid = blockIdx.x*256 + threadIdx.x;   // [0, B*T)
    int t = gid >> 9;                          // /NB
    int b = gid & (NB-1);
    int tok = x[(size_t)b*NT + t];
    const float4* tp = (const float4*)tab + (size_t)tok*2;
    float4 v0 = tp[0], v1 = tp[1];
    gx[(size_t)gid*2]   = v0;                  // coalesced write
    gx[(size_t)gid*2+1] = v1;
}

// K2: scan. 2 lanes/row (lane k owns h[k],c[k] both layers), 16 blocks x 64 = 16 waves.
// gx is a coalesced stream, 4-deep register prefetch; shuffles are DPP (cheap).
__global__ __launch_bounds__(64) void lstm_scan(const float4* __restrict__ gx,
                                                const float* __restrict__ Whh0,
                                                const float* __restrict__ Wih1,
                                                const float* __restrict__ Whh1,
                                                const float* __restrict__ b1,
                                                float* __restrict__ y1out,   // [T][B][2]
                                                float* __restrict__ tail){
    const int tid = threadIdx.x;
    const int k = tid & 1;
    const int row = blockIdx.x*32 + (tid>>1);
    float w00[4],w01[4],wi0[4],wi1[4],wh0[4],wh1[4],bg[4];
#pragma unroll
    for (int g=0; g<4; g++){
        int j = 2*g+k;
        float s = (j==4||j==5) ? 2.0f*L2E : L2E;
        w00[g]=Whh0[j*2+k]*s;  w01[g]=Whh0[j*2+(k^1)]*s;
        wi0[g]=Wih1[j*2+k]*s;  wi1[g]=Wih1[j*2+(k^1)]*s;
        wh0[g]=Whh1[j*2+k]*s;  wh1[g]=Whh1[j*2+(k^1)]*s;
        bg[g]=b1[j]*s;
    }
    const size_t S = (size_t)NB*2;             // float4 stride per t
    const float4* __restrict__ gp = gx + (size_t)row*2 + k;
    float h0=0.f,c0=0.f,h1=0.f,c1=0.f;
    float4 fA = gp[0*S], fB = gp[1*S], fC = gp[2*S], fD = gp[3*S];

#define STEP(F, T, PFT) { \
    float4 nf = gp[(size_t)(PFT)*S]; \
    float ho = __shfl_xor(h0,1); \
    float ai = fmaf(w00[0],h0, fmaf(w01[0],ho, F.x)); \
    float af = fmaf(w00[1],h0, fmaf(w01[1],ho, F.y)); \
    float ag = fmaf(w00[2],h0, fmaf(w01[2],ho, F.z)); \
    float ao = fmaf(w00[3],h0, fmaf(w01[3],ho, F.w)); \
    float si=sig_s(ai), sf=sig_s(af), tg=tanh_s2(ag), so=sig_s(ao); \
    c0 = fmaf(sf,c0, si*tg); \
    h0 = so*tanh_n(c0); \
    float h0o = __shfl_xor(h0,1); \
    float h1o = __shfl_xor(h1,1); \
    float q0 = fmaf(wh0[0],h1, fmaf(wh1[0],h1o, fmaf(wi0[0],h0, fmaf(wi1[0],h0o, bg[0])))); \
    float q1 = fmaf(wh0[1],h1, fmaf(wh1[1],h1o, fmaf(wi0[1],h0, fmaf(wi1[1],h0o, bg[1])))); \
    float q2 = fmaf(wh0[2],h1, fmaf(wh1[2],h1o, fmaf(wi0[2],h0, fmaf(wi1[2],h0o, bg[2])))); \
    float q3 = fmaf(wh0[3],h1, fmaf(wh1[3],h1o, fmaf(wi0[3],h0, fmaf(wi1[3],h0o, bg[3])))); \
    float ti=sig_s(q0), tf=sig_s(q1), th=tanh_s2(q2), to=sig_s(q3); \
    c1 = fmaf(tf,c1, ti*th); \
    h1 = to*tanh_n(c1); \
    y1out[((size_t)(T)*NB + row)*2 + k] = h1; \
    F = nf; }

    for (int t=0; t<NT; t+=4){
        STEP(fA, t+0, t+4)
        STEP(fB, t+1, t+5)
        STEP(fC, t+2, t+6)
        STEP(fD, t+3, t+7)   // prefetch reads ≤ gx[NT+3] — still inside d_out, safe
    }
#undef STEP
    tail[row*2+k]            = h0;   // h_n[0]
    tail[NB*2 + row*2+k]     = h1;   // h_n[1]
    tail[2*NB*2 + row*2+k]   = c0;   // c_n[0]
    tail[3*NB*2 + row*2+k]   = c1;   // c_n[1]
}

// K3: out[bt][j] = y1[bt]·Wfc[j] + bfc[j]; one float4 store per thread.
__global__ __launch_bounds__(256) void fc_out(const float* __restrict__ y1,
                                              const float* __restrict__ Wfc,
                                              const float* __restrict__ bfc,
                                              float* __restrict__ out){
    const int tid = threadIdx.x;
    const int j4  = tid & 31;
    const int btl = tid >> 5;
    const int bt  = blockIdx.x*8 + btl;
    const int b   = bt >> 11;
    const int tt  = bt & (NT-1);
    const float2 y  = *(const float2*)(y1 + ((size_t)tt*NB + b)*2);
    const float4 wa = *(const float4*)(Wfc + j4*8);
    const float4 wb = *(const float4*)(Wfc + j4*8+4);
    const float4 bbv= *(const float4*)(bfc + j4*4);
    float4 o;
    o.x = fmaf(y.x,wa.x, fmaf(y.y,wa.y, bbv.x));
    o.y = fmaf(y.x,wa.z, fmaf(y.y,wa.w, bbv.y));
    o.z = fmaf(y.x,wb.x, fmaf(y.y,wb.y, bbv.z));
    o.w = fmaf(y.x,wb.z, fmaf(y.y,wb.w, bbv.w));
    *(float4*)(out + (size_t)bt*128 + j4*4) = o;
}

extern "C" void kernel_launch(void* const* d_in, const int* in_sizes, int n_in,
                              void* d_out, int out_size, void* d_ws, size_t ws_size,
                              hipStream_t stream){
    const int*   x    = (const int*)d_in[0];
    const float* emb  = (const float*)d_in[1];
    const float* Wih0 = (const float*)d_in[2];
    const float* Whh0 = (const float*)d_in[3];
    const float* b0   = (const float*)d_in[4];
    const float* Wih1 = (const float*)d_in[5];
    const float* Whh1 = (const float*)d_in[6];
    const float* b1   = (const float*)d_in[7];
    const float* Wfc  = (const float*)d_in[8];
    const float* bfc  = (const float*)d_in[9];
    float* out  = (float*)d_out;
    float* tab  = (float*)d_ws;                       // VOCAB*8 floats = 1.6 MB
    float* y1   = tab + (size_t)VOCAB*8;              // T*B*2 floats = 8 MB
    float* tail = out + (size_t)NB*NT*NOUT;           // h_n|c_n region of d_out
    float4* gxs = (float4*)d_out;                     // 32 MB scratch in out; overwritten by fc_out afterwards

    build_table<<<(VOCAB+255)/256, 256, 0, stream>>>(emb, Wih0, b0, tab);
    expand_gates<<<(NB*NT)/256, 256, 0, stream>>>(x, tab, gxs);
    lstm_scan<<<16, 64, 0, stream>>>(gxs, Whh0, Wih1, Whh1, b1, y1, tail);
    fc_out<<<(NB*NT)/8, 256, 0, stream>>>(y1, Wfc, bfc, out);
}